// Round 4
// baseline (367.161 us; speedup 1.0000x reference)
//
#include <hip/hip_runtime.h>
#include <math.h>

#define BN 256
#define SN 196
#define RN 1024
#define HN 512
#define KSPLIT 8
#define KCH 128   // per block: two 64-wide sub-chunks, LDS reused

__device__ __forceinline__ float fast_tanh(float x) {
    // tanh(x) = 1 - 2/(exp(2x)+1); exact saturation at +/-inf
    float e = __expf(2.0f * x);
    return 1.0f - 2.0f * __builtin_amdgcn_rcpf(e + 1.0f);
}

// ---------------- kernel 1: split-K GEMM partials ----------------
// partial[kc][b][h] = hidden[b, kc*128:(kc+1)*128] . w[h, kc*128:(kc+1)*128]
// grid (4 b-tiles, 8 h-tiles, 8 k-chunks) = 256 blocks, 256 thr.
__global__ __launch_bounds__(256) void k_gemm_partial(
    const float* __restrict__ hidden, const float* __restrict__ w,
    float* __restrict__ partial) {
    __shared__ float At[64][64];
    __shared__ float Bt[64][64];
    const int t  = threadIdx.x;
    const int b0 = blockIdx.x * 64;
    const int h0 = blockIdx.y * 64;
    const int kc = blockIdx.z;

    const int th4 = (t & 15) * 4;
    const int tb4 = (t >> 4) * 4;
    float4 acc0 = {0,0,0,0}, acc1 = {0,0,0,0}, acc2 = {0,0,0,0}, acc3 = {0,0,0,0};

    for (int sub = 0; sub < 2; ++sub) {
        const int k0 = kc * KCH + sub * 64;
        {   // cooperative load + transpose
            const int row = t >> 2, kq = (t & 3) * 16;
            const float* srcA = hidden + (size_t)(b0 + row) * RN + k0 + kq;
            const float* srcB = w      + (size_t)(h0 + row) * RN + k0 + kq;
#pragma unroll
            for (int j = 0; j < 4; ++j) {
                float4 v = *(const float4*)(srcA + j * 4);
                int k = kq + j * 4;
                At[k][row] = v.x; At[k+1][row] = v.y; At[k+2][row] = v.z; At[k+3][row] = v.w;
            }
#pragma unroll
            for (int j = 0; j < 4; ++j) {
                float4 v = *(const float4*)(srcB + j * 4);
                int k = kq + j * 4;
                Bt[k][row] = v.x; Bt[k+1][row] = v.y; Bt[k+2][row] = v.z; Bt[k+3][row] = v.w;
            }
        }
        __syncthreads();
#pragma unroll 8
        for (int k = 0; k < 64; ++k) {
            float4 a  = *(const float4*)&At[k][tb4];
            float4 bb = *(const float4*)&Bt[k][th4];
            acc0.x = fmaf(a.x, bb.x, acc0.x); acc0.y = fmaf(a.x, bb.y, acc0.y);
            acc0.z = fmaf(a.x, bb.z, acc0.z); acc0.w = fmaf(a.x, bb.w, acc0.w);
            acc1.x = fmaf(a.y, bb.x, acc1.x); acc1.y = fmaf(a.y, bb.y, acc1.y);
            acc1.z = fmaf(a.y, bb.z, acc1.z); acc1.w = fmaf(a.y, bb.w, acc1.w);
            acc2.x = fmaf(a.z, bb.x, acc2.x); acc2.y = fmaf(a.z, bb.y, acc2.y);
            acc2.z = fmaf(a.z, bb.z, acc2.z); acc2.w = fmaf(a.z, bb.w, acc2.w);
            acc3.x = fmaf(a.w, bb.x, acc3.x); acc3.y = fmaf(a.w, bb.y, acc3.y);
            acc3.z = fmaf(a.w, bb.z, acc3.z); acc3.w = fmaf(a.w, bb.w, acc3.w);
        }
        __syncthreads();
    }
    float* dst = partial + ((size_t)kc * BN + b0 + tb4) * HN + h0 + th4;
    *(float4*)(dst)          = acc0;
    *(float4*)(dst + HN)     = acc1;
    *(float4*)(dst + 2 * HN) = acc2;
    *(float4*)(dst + 3 * HN) = acc3;
}

// ---------------- kernel 2: att_h[b,h] = bias[h] + sum_kc partial[kc][b][h] ----------------
__global__ __launch_bounds__(128) void k_reduce(
    const float* __restrict__ partial, const float* __restrict__ bias,
    float* __restrict__ att_h) {
    const int b = blockIdx.x, t = threadIdx.x;
    float4 s = *(const float4*)(bias + t * 4);
    const float* p = partial + (size_t)b * HN + t * 4;
#pragma unroll
    for (int kc = 0; kc < KSPLIT; ++kc) {
        float4 v = *(const float4*)(p + (size_t)kc * BN * HN);
        s.x += v.x; s.y += v.y; s.z += v.z; s.w += v.w;
    }
    *(float4*)(att_h + (size_t)b * HN + t * 4) = s;
}

// ---------------- kernel 3: scores[b,s] (alpha_b dropped: softmax shift-invariant) ---------
// one wave per (b,s); 12544 blocks x 4 waves = 50176 waves exactly.
__global__ __launch_bounds__(256) void k_scores(
    const float* __restrict__ p_att, const float* __restrict__ in_w,
    const float* __restrict__ att_h, const float* __restrict__ alpha_w,
    float* __restrict__ scores) {
    const int lane = threadIdx.x & 63;
    const int gid  = blockIdx.x * 4 + (threadIdx.x >> 6);   // b*196 + s
    const int b    = gid / SN;

    const float iw = in_w[gid];
    const float4* p4 = (const float4*)(p_att + (size_t)gid * HN);
    const float4* a4 = (const float4*)(alpha_w);
    const float4* h4 = (const float4*)(att_h + (size_t)b * HN);

    float4 p0 = p4[lane], p1 = p4[lane + 64];
    float4 aw0 = a4[lane], aw1 = a4[lane + 64];
    float4 ah0 = h4[lane], ah1 = h4[lane + 64];

    float sum;
    sum  = fast_tanh(fmaf(iw, p0.x, ah0.x)) * aw0.x;
    sum += fast_tanh(fmaf(iw, p0.y, ah0.y)) * aw0.y;
    sum += fast_tanh(fmaf(iw, p0.z, ah0.z)) * aw0.z;
    sum += fast_tanh(fmaf(iw, p0.w, ah0.w)) * aw0.w;
    sum += fast_tanh(fmaf(iw, p1.x, ah1.x)) * aw1.x;
    sum += fast_tanh(fmaf(iw, p1.y, ah1.y)) * aw1.y;
    sum += fast_tanh(fmaf(iw, p1.z, ah1.z)) * aw1.z;
    sum += fast_tanh(fmaf(iw, p1.w, ah1.w)) * aw1.w;
#pragma unroll
    for (int off = 32; off; off >>= 1) sum += __shfl_xor(sum, off, 64);
    if (lane == 0) scores[gid] = sum;
}

// ---------------- kernel 4: in-place softmax over s (196) per b ----------------
// 4 chunks of 64 cover all 196 (192..195 in chunk 3, lanes 0..3) — R3's bug was
// using only 3 chunks (max s=191), leaving raw scores in 192..195.
__global__ __launch_bounds__(64) void k_softmax(float* __restrict__ wout) {
    const int b = blockIdx.x, lane = threadIdx.x;
    float* row = wout + (size_t)b * SN;

    float v[4];
    float m = -1e30f;
#pragma unroll
    for (int i = 0; i < 4; ++i) {
        int s = lane + i * 64;
        v[i] = (s < SN) ? row[s] : -1e30f;
        m = fmaxf(m, v[i]);
    }
#pragma unroll
    for (int off = 32; off; off >>= 1) m = fmaxf(m, __shfl_xor(m, off, 64));

    float e[4];
    float sum = 0.f;
#pragma unroll
    for (int i = 0; i < 4; ++i) {
        int s = lane + i * 64;
        e[i] = (s < SN) ? __expf(v[i] - m) : 0.f;
        sum += e[i];
    }
#pragma unroll
    for (int off = 32; off; off >>= 1) sum += __shfl_xor(sum, off, 64);

    float inv = 1.0f / sum;
#pragma unroll
    for (int i = 0; i < 4; ++i) {
        int s = lane + i * 64;
        if (s < SN) row[s] = e[i] * inv;
    }
}

// ---------------- kernel 5: att_res[b,r] = sum_s weight[b,s] * att_feats[b,s,r] ------------
// 512 blocks (b, r-half), 128 thr, float4/thread; s unrolled x14 -> 28 KB in flight/block.
__global__ __launch_bounds__(128) void k_pool(
    const float* __restrict__ att_feats, const float* __restrict__ weight,
    float* __restrict__ att_res) {
    __shared__ float w[SN];
    const int b    = blockIdx.x >> 1;
    const int half = blockIdx.x & 1;
    const int t    = threadIdx.x;

    for (int s = t; s < SN; s += 128) w[s] = weight[(size_t)b * SN + s];
    __syncthreads();

    const float* base = att_feats + (size_t)b * SN * RN + half * 512 + t * 4;
    float4 acc = {0, 0, 0, 0};
    for (int i = 0; i < SN; i += 14) {       // 196 = 14 * 14
#pragma unroll
        for (int j = 0; j < 14; ++j) {
            int s = i + j;
            float ws = w[s];
            float4 v = *(const float4*)(base + (size_t)s * RN);
            acc.x = fmaf(ws, v.x, acc.x);
            acc.y = fmaf(ws, v.y, acc.y);
            acc.z = fmaf(ws, v.z, acc.z);
            acc.w = fmaf(ws, v.w, acc.w);
        }
    }
    *(float4*)(att_res + (size_t)b * RN + half * 512 + t * 4) = acc;
}

extern "C" void kernel_launch(void* const* d_in, const int* in_sizes, int n_in,
                              void* d_out, int out_size, void* d_ws, size_t ws_size,
                              hipStream_t stream) {
    const float* att_feats   = (const float*)d_in[0];  // [B,S,R]
    const float* p_att_feats = (const float*)d_in[1];  // [B,S,H]
    const float* hidden      = (const float*)d_in[2];  // [B,R]
    const float* in_weights  = (const float*)d_in[3];  // [B,S]
    const float* h2att_w     = (const float*)d_in[4];  // [H,R]
    const float* h2att_b     = (const float*)d_in[5];  // [H]
    const float* alpha_w     = (const float*)d_in[6];  // [1,H]

    float* att_res = (float*)d_out;                    // [B,R]
    float* weight  = (float*)d_out + BN * RN;          // [B,S]
    float* partial = (float*)d_ws;                     // [KSPLIT,B,H] = 4 MB
    float* att_h   = (float*)d_ws + (size_t)KSPLIT * BN * HN;  // [B,H] at 4 MB (<= R2-proven 8 MB)

    k_gemm_partial<<<dim3(BN / 64, HN / 64, KSPLIT), 256, 0, stream>>>(hidden, h2att_w, partial);
    k_reduce <<<BN, 128, 0, stream>>>(partial, h2att_b, att_h);
    k_scores <<<(BN * SN) / 4, 256, 0, stream>>>(p_att_feats, in_weights, att_h, alpha_w, weight);
    k_softmax<<<BN, 64, 0, stream>>>(weight);
    k_pool   <<<BN * 2, 128, 0, stream>>>(att_feats, weight, att_res);
}

// Round 5
// 361.286 us; speedup vs baseline: 1.0163x; 1.0163x over previous
//
#include <hip/hip_runtime.h>
#include <math.h>

#define BN 256
#define SN 196
#define RN 1024
#define HN 512
#define KSPLIT 8
#define KCH 128   // per gemm block: two 64-wide sub-chunks, LDS reused

__device__ __forceinline__ float fast_tanh(float x) {
    // tanh(x) = 1 - 2/(exp(2x)+1); exact saturation at +/-inf
    float e = __expf(2.0f * x);
    return 1.0f - 2.0f * __builtin_amdgcn_rcpf(e + 1.0f);
}

// ---------------- kernel 1: split-K GEMM partials ----------------
// partial[kc][b][h] = hidden[b, kc*128:(kc+1)*128] . w[h, kc*128:(kc+1)*128]
// grid (4 b-tiles, 8 h-tiles, 8 k-chunks) = 256 blocks, 256 thr.
__global__ __launch_bounds__(256) void k_gemm_partial(
    const float* __restrict__ hidden, const float* __restrict__ w,
    float* __restrict__ partial) {
    __shared__ float At[64][64];
    __shared__ float Bt[64][64];
    const int t  = threadIdx.x;
    const int b0 = blockIdx.x * 64;
    const int h0 = blockIdx.y * 64;
    const int kc = blockIdx.z;

    const int th4 = (t & 15) * 4;
    const int tb4 = (t >> 4) * 4;
    float4 acc0 = {0,0,0,0}, acc1 = {0,0,0,0}, acc2 = {0,0,0,0}, acc3 = {0,0,0,0};

    for (int sub = 0; sub < 2; ++sub) {
        const int k0 = kc * KCH + sub * 64;
        {   // cooperative load + transpose
            const int row = t >> 2, kq = (t & 3) * 16;
            const float* srcA = hidden + (size_t)(b0 + row) * RN + k0 + kq;
            const float* srcB = w      + (size_t)(h0 + row) * RN + k0 + kq;
#pragma unroll
            for (int j = 0; j < 4; ++j) {
                float4 v = *(const float4*)(srcA + j * 4);
                int k = kq + j * 4;
                At[k][row] = v.x; At[k+1][row] = v.y; At[k+2][row] = v.z; At[k+3][row] = v.w;
            }
#pragma unroll
            for (int j = 0; j < 4; ++j) {
                float4 v = *(const float4*)(srcB + j * 4);
                int k = kq + j * 4;
                Bt[k][row] = v.x; Bt[k+1][row] = v.y; Bt[k+2][row] = v.z; Bt[k+3][row] = v.w;
            }
        }
        __syncthreads();
#pragma unroll 8
        for (int k = 0; k < 64; ++k) {
            float4 a  = *(const float4*)&At[k][tb4];
            float4 bb = *(const float4*)&Bt[k][th4];
            acc0.x = fmaf(a.x, bb.x, acc0.x); acc0.y = fmaf(a.x, bb.y, acc0.y);
            acc0.z = fmaf(a.x, bb.z, acc0.z); acc0.w = fmaf(a.x, bb.w, acc0.w);
            acc1.x = fmaf(a.y, bb.x, acc1.x); acc1.y = fmaf(a.y, bb.y, acc1.y);
            acc1.z = fmaf(a.y, bb.z, acc1.z); acc1.w = fmaf(a.y, bb.w, acc1.w);
            acc2.x = fmaf(a.z, bb.x, acc2.x); acc2.y = fmaf(a.z, bb.y, acc2.y);
            acc2.z = fmaf(a.z, bb.z, acc2.z); acc2.w = fmaf(a.z, bb.w, acc2.w);
            acc3.x = fmaf(a.w, bb.x, acc3.x); acc3.y = fmaf(a.w, bb.y, acc3.y);
            acc3.z = fmaf(a.w, bb.z, acc3.z); acc3.w = fmaf(a.w, bb.w, acc3.w);
        }
        __syncthreads();
    }
    float* dst = partial + ((size_t)kc * BN + b0 + tb4) * HN + h0 + th4;
    *(float4*)(dst)          = acc0;
    *(float4*)(dst + HN)     = acc1;
    *(float4*)(dst + 2 * HN) = acc2;
    *(float4*)(dst + 3 * HN) = acc3;
}

// ---------------- kernel 2: fused per-b reduce + scores + softmax + pool ----------------
// 256 blocks (1/CU) x 1024 threads (16 waves). Proven in R2; KSPLIT now 8.
__global__ __launch_bounds__(1024) void k_fused(
    const float* __restrict__ partial, const float* __restrict__ bias,
    const float* __restrict__ p_att, const float* __restrict__ in_w,
    const float* __restrict__ alpha_w, const float* __restrict__ att_feats,
    float* __restrict__ att_res, float* __restrict__ weight_out) {
    __shared__ float att_h[HN];        // 2 KB
    __shared__ float sc[256];          // scores (196 used, rest -1e30)
    __shared__ float red[16 * 256];    // 16 KB pool partials
    const int b    = blockIdx.x;
    const int t    = threadIdx.x;
    const int wv   = t >> 6;
    const int lane = t & 63;

    if (t >= SN && t < 256) sc[t] = -1e30f;

    // phase 0: att_h[h] = bias[h] + sum_kc partial[kc][b][h]
    if (t < 128) {
        float4 s = *(const float4*)(bias + t * 4);
        const float* p = partial + (size_t)b * HN + t * 4;
#pragma unroll
        for (int kc = 0; kc < KSPLIT; ++kc) {
            float4 v = *(const float4*)(p + (size_t)kc * BN * HN);
            s.x += v.x; s.y += v.y; s.z += v.z; s.w += v.w;
        }
        *(float4*)&att_h[t * 4] = s;
    }
    __syncthreads();

    // phase 1: scores[s] = sum_h tanh(iw*p + att_h) * alpha_w  (alpha_b dropped:
    // softmax is shift-invariant, so it cannot affect either output)
    {
        const float4* a4 = (const float4*)alpha_w;
        float4 aw0 = a4[lane], aw1 = a4[lane + 64];
        float4 ah0 = *(const float4*)&att_h[lane * 4];
        float4 ah1 = *(const float4*)&att_h[(lane + 64) * 4];
        const float4* p4 = (const float4*)p_att;
        for (int si = wv; si < SN; si += 16) {
            float  iw = in_w[b * SN + si];
            size_t rb = (size_t)(b * SN + si) * (HN / 4);
            float4 p0 = p4[rb + lane];
            float4 p1 = p4[rb + lane + 64];
            float sum;
            sum  = fast_tanh(fmaf(iw, p0.x, ah0.x)) * aw0.x;
            sum += fast_tanh(fmaf(iw, p0.y, ah0.y)) * aw0.y;
            sum += fast_tanh(fmaf(iw, p0.z, ah0.z)) * aw0.z;
            sum += fast_tanh(fmaf(iw, p0.w, ah0.w)) * aw0.w;
            sum += fast_tanh(fmaf(iw, p1.x, ah1.x)) * aw1.x;
            sum += fast_tanh(fmaf(iw, p1.y, ah1.y)) * aw1.y;
            sum += fast_tanh(fmaf(iw, p1.z, ah1.z)) * aw1.z;
            sum += fast_tanh(fmaf(iw, p1.w, ah1.w)) * aw1.w;
#pragma unroll
            for (int off = 32; off; off >>= 1) sum += __shfl_xor(sum, off, 64);
            if (lane == 0) sc[si] = sum;
        }
    }
    __syncthreads();

    // phase 2: softmax over 196 (wave 0 only), normalized weights -> sc + global out
    if (wv == 0) {
        float v0 = sc[lane], v1 = sc[lane + 64], v2 = sc[lane + 128], v3 = sc[lane + 192];
        float m = fmaxf(fmaxf(v0, v1), fmaxf(v2, v3));
#pragma unroll
        for (int off = 32; off; off >>= 1) m = fmaxf(m, __shfl_xor(m, off, 64));
        float e0 = __expf(v0 - m), e1 = __expf(v1 - m);
        float e2 = __expf(v2 - m), e3 = __expf(v3 - m);
        float s = e0 + e1 + e2 + e3;
#pragma unroll
        for (int off = 32; off; off >>= 1) s += __shfl_xor(s, off, 64);
        float inv = 1.0f / s;
        e0 *= inv; e1 *= inv; e2 *= inv; e3 *= inv;
        sc[lane] = e0; sc[lane + 64] = e1; sc[lane + 128] = e2; sc[lane + 192] = e3;
        float* wo = weight_out + (size_t)b * SN;
        wo[lane] = e0; wo[lane + 64] = e1; wo[lane + 128] = e2;
        if (lane + 192 < SN) wo[lane + 192] = e3;
    }
    __syncthreads();

    // phase 3: att_res[r] = sum_s weight[s] * att_feats[b,s,r]
    // wave -> (s-group g, r-quarter q); 49 s per wave, unroll 7 (7 KB in flight/wave)
    {
        const int g = wv >> 2, q = wv & 3;
        const float* base = att_feats + (size_t)b * SN * RN + q * 256 + lane * 4;
        float4 acc = {0,0,0,0};
        for (int i = 0; i < 49; i += 7) {
#pragma unroll
            for (int j = 0; j < 7; ++j) {
                int s = g + 4 * (i + j);
                float ws = sc[s];
                float4 v = *(const float4*)(base + (size_t)s * RN);
                acc.x = fmaf(ws, v.x, acc.x);
                acc.y = fmaf(ws, v.y, acc.y);
                acc.z = fmaf(ws, v.z, acc.z);
                acc.w = fmaf(ws, v.w, acc.w);
            }
        }
        *(float4*)&red[wv * 256 + lane * 4] = acc;
    }
    __syncthreads();
    {
        const int q2 = t >> 8, rr = t & 255;
        float r = red[q2 * 256 + rr] + red[(4 + q2) * 256 + rr]
                + red[(8 + q2) * 256 + rr] + red[(12 + q2) * 256 + rr];
        att_res[(size_t)b * RN + t] = r;
    }
}

extern "C" void kernel_launch(void* const* d_in, const int* in_sizes, int n_in,
                              void* d_out, int out_size, void* d_ws, size_t ws_size,
                              hipStream_t stream) {
    const float* att_feats   = (const float*)d_in[0];  // [B,S,R]
    const float* p_att_feats = (const float*)d_in[1];  // [B,S,H]
    const float* hidden      = (const float*)d_in[2];  // [B,R]
    const float* in_weights  = (const float*)d_in[3];  // [B,S]
    const float* h2att_w     = (const float*)d_in[4];  // [H,R]
    const float* h2att_b     = (const float*)d_in[5];  // [H]
    const float* alpha_w     = (const float*)d_in[6];  // [1,H]

    float* att_res = (float*)d_out;                    // [B,R]
    float* weight  = (float*)d_out + BN * RN;          // [B,S]
    float* partial = (float*)d_ws;                     // [KSPLIT,B,H] = 4 MB

    k_gemm_partial<<<dim3(BN / 64, HN / 64, KSPLIT), 256, 0, stream>>>(hidden, h2att_w, partial);
    k_fused<<<BN, 1024, 0, stream>>>(partial, h2att_b, p_att_feats, in_weights,
                                     alpha_w, att_feats, att_res, weight);
}